// Round 5
// baseline (884.105 us; speedup 1.0000x reference)
//
#include <hip/hip_runtime.h>
#include <stdint.h>

#define TSTEPS 1024
#define L2E 1.4426950408889634f

typedef float v2f __attribute__((ext_vector_type(2)));

__device__ __forceinline__ float rcpf_(float v) { return __builtin_amdgcn_rcpf(v); }
__device__ __forceinline__ float ex2(float v) { return __builtin_amdgcn_exp2f(v); }
#define PKFMA(a, b, c) __builtin_elementwise_fma((a), (b), (c))

// DPP quad-permute move (pure VALU; fuses into v_add_f32_dpp)
#define DPP_X1 0xB1  // quad_perm [1,0,3,2]  (xor 1)
#define DPP_X2 0x4E  // quad_perm [2,3,0,1]  (xor 2)
template <int CTRL>
__device__ __forceinline__ float dppf(float v) {
    return __int_as_float(__builtin_amdgcn_update_dpp(
        0, __float_as_int(v), CTRL, 0xF, 0xF, true));
}
// sum over the 4 lanes of a hardware quad
__device__ __forceinline__ float qsum(float v) {
    v += dppf<DPP_X1>(v);
    v += dppf<DPP_X2>(v);
    return v;
}

// Opaque loads: value is asm-produced -> cannot be rematerialized as a load.
__device__ __forceinline__ v2f ldg2(const float* p) {
    v2f r; uint64_t a = (uint64_t)p;
    asm volatile("global_load_dwordx2 %0, %1, off\n\ts_waitcnt vmcnt(0)"
                 : "=v"(r) : "v"(a));
    return r;
}
__device__ __forceinline__ float ldg1(const float* p) {
    float r; uint64_t a = (uint64_t)p;
    asm volatile("global_load_dword %0, %1, off\n\ts_waitcnt vmcnt(0)"
                 : "=v"(r) : "v"(a));
    return r;
}

__global__ __launch_bounds__(256, 4) void gru3_quad(
    const float* __restrict__ x,      // [4096,1024,1]
    const float* __restrict__ w_ih0,  // [48,1]
    const float* __restrict__ w_ih12, // [2,48,16]
    const float* __restrict__ w_hh,   // [3,48,16]
    const float* __restrict__ b_ih,   // [3,48]
    const float* __restrict__ b_hh,   // [3,48]
    const float* __restrict__ fc_w,   // [5,16]
    const float* __restrict__ fc_b,   // [5]
    float* __restrict__ out)          // [4096,5]
{
    __shared__ float xs[4][TSTEPS];  // 16 KB: one x row per wave
    __shared__ float hb[4][4][16];   // [wave][layer0..2 + dummy][unit]

    const int lane = threadIdx.x & 63;
    const int wv = threadIdx.x >> 6;   // wave in block = sequence slot
    const int u = lane >> 2;           // hidden unit (0..15)
    const int g = lane & 3;            // colgroup (matvec) & role (gates)
    const int seq = blockIdx.x * 4 + wv;

    // ---- stage x (coalesced float4) + zero h buffers
    {
        const float4* xg = (const float4*)(x + (size_t)blockIdx.x * 4 * TSTEPS);
        float4* xs4 = (float4*)&xs[0][0];
#pragma unroll
        for (int j = 0; j < 4; ++j)
            xs4[threadIdx.x + 256 * j] = xg[threadIdx.x + 256 * j];
        hb[wv][g][u] = 0.f;  // 64 lanes cover all 4x16 slots incl dummy row
    }

    // ---- per-lane weights: unit u's rows, cols 4g..4g+3 (pinned via asm)
    v2f wh[3][3][2];  // [layer][gate r,z,n][col pair]
    v2f wi[2][3][2];  // layers 1,2 input-side
#pragma unroll
    for (int l = 0; l < 3; ++l)
#pragma unroll
        for (int q = 0; q < 3; ++q)
#pragma unroll
            for (int m = 0; m < 2; ++m)
                wh[l][q][m] = ldg2(w_hh + (l * 48 + q * 16 + u) * 16 + 4 * g + 2 * m);
#pragma unroll
    for (int l = 0; l < 2; ++l)
#pragma unroll
        for (int q = 0; q < 3; ++q)
#pragma unroll
            for (int m = 0; m < 2; ++m)
                wi[l][q][m] = ldg2(w_ih12 + (l * 48 + q * 16 + u) * 16 + 4 * g + 2 * m);

    float cbr[3], cbz[3], bnh[3], bnx[3];
#pragma unroll
    for (int l = 0; l < 3; ++l) {
        cbr[l] = ldg1(b_ih + l * 48 + u) + ldg1(b_hh + l * 48 + u);
        cbz[l] = ldg1(b_ih + l * 48 + 16 + u) + ldg1(b_hh + l * 48 + 16 + u);
        bnh[l] = ldg1(b_hh + l * 48 + 32 + u);
        bnx[l] = ldg1(b_ih + l * 48 + 32 + u);
    }
    const float wxr = ldg1(w_ih0 + u);
    const float wxz = ldg1(w_ih0 + 16 + u);
    const float wxn = ldg1(w_ih0 + 32 + u);

    __syncthreads();  // xs + hb ready

    // ---- state: h col-slices (this lane's 4 cols) + own tracked h[u] (role g)
    v2f hs0[2] = {{0.f, 0.f}, {0.f, 0.f}};
    v2f hs1[2] = {{0.f, 0.f}, {0.f, 0.f}};
    v2f hs2[2] = {{0.f, 0.f}, {0.f, 0.f}};
    float hp = 0.f;

    const bool godd = (g & 1);
    const bool g1m = (g == 1), g2m = (g == 2), g3m = (g == 3);
    float* hw = &hb[wv][g][u];  // role-g write slot (g3 -> dummy)

    auto step = [&](bool F0, bool F1, bool F2, int t0) {
        float xt = F0 ? xs[wv][t0] : 0.f;
        float sr0 = 0.f, sz0 = 0.f, sn0 = 0.f, sx0 = 0.f;
        float sr1 = 0.f, sz1 = 0.f, sn1 = 0.f, sx1 = 0.f;
        float sr2 = 0.f, sz2 = 0.f, sn2 = 0.f, sx2 = 0.f;
        v2f a;
        // ---- matvec partials over this lane's 4 cols, quad-reduce, bias after
        if (F0) {
            a = wh[0][0][0] * hs0[0]; a = PKFMA(wh[0][0][1], hs0[1], a);
            sr0 = fmaf(wxr, xt, cbr[0] + qsum(a.x + a.y));
            a = wh[0][1][0] * hs0[0]; a = PKFMA(wh[0][1][1], hs0[1], a);
            sz0 = fmaf(wxz, xt, cbz[0] + qsum(a.x + a.y));
            a = wh[0][2][0] * hs0[0]; a = PKFMA(wh[0][2][1], hs0[1], a);
            sn0 = bnh[0] + qsum(a.x + a.y);
            sx0 = fmaf(wxn, xt, bnx[0]);  // scalar input side: no reduce
        }
        if (F1) {
            a = wh[1][0][0] * hs1[0]; a = PKFMA(wh[1][0][1], hs1[1], a);
            a = PKFMA(wi[0][0][0], hs0[0], a); a = PKFMA(wi[0][0][1], hs0[1], a);
            sr1 = cbr[1] + qsum(a.x + a.y);
            a = wh[1][1][0] * hs1[0]; a = PKFMA(wh[1][1][1], hs1[1], a);
            a = PKFMA(wi[0][1][0], hs0[0], a); a = PKFMA(wi[0][1][1], hs0[1], a);
            sz1 = cbz[1] + qsum(a.x + a.y);
            a = wh[1][2][0] * hs1[0]; a = PKFMA(wh[1][2][1], hs1[1], a);
            sn1 = bnh[1] + qsum(a.x + a.y);
            a = wi[0][2][0] * hs0[0]; a = PKFMA(wi[0][2][1], hs0[1], a);
            sx1 = bnx[1] + qsum(a.x + a.y);
        }
        if (F2) {
            a = wh[2][0][0] * hs2[0]; a = PKFMA(wh[2][0][1], hs2[1], a);
            a = PKFMA(wi[1][0][0], hs1[0], a); a = PKFMA(wi[1][0][1], hs1[1], a);
            sr2 = cbr[2] + qsum(a.x + a.y);
            a = wh[2][1][0] * hs2[0]; a = PKFMA(wh[2][1][1], hs2[1], a);
            a = PKFMA(wi[1][1][0], hs1[0], a); a = PKFMA(wi[1][1][1], hs1[1], a);
            sz2 = cbz[2] + qsum(a.x + a.y);
            a = wh[2][2][0] * hs2[0]; a = PKFMA(wh[2][2][1], hs2[1], a);
            sn2 = bnh[2] + qsum(a.x + a.y);
            a = wi[1][2][0] * hs1[0]; a = PKFMA(wi[1][2][1], hs1[1], a);
            sx2 = bnx[2] + qsum(a.x + a.y);
        }
        // ---- sigmoid streams: even lanes compute r, odd lanes z; swap via DPP
        float v0 = godd ? sz0 : sr0;
        float sg0 = rcpf_(1.f + ex2(v0 * -L2E));
        float ot0 = dppf<DPP_X1>(sg0);
        float v1 = godd ? sz1 : sr1;
        float sg1 = rcpf_(1.f + ex2(v1 * -L2E));
        float ot1 = dppf<DPP_X1>(sg1);
        float v2_ = godd ? sz2 : sr2;
        float sg2 = rcpf_(1.f + ex2(v2_ * -L2E));
        float ot2 = dppf<DPP_X1>(sg2);
        // ---- batched tanh: lane g handles layer g (g3 = don't care)
        float rsel = g1m ? ot1 : (g2m ? sg2 : sg0);  // r_Lg at lane g
        float ahs  = g1m ? sn1 : (g2m ? sn2 : sn0);
        float axs  = g1m ? sx1 : (g2m ? sx2 : sx0);
        float ut = fmaf(rsel, ahs, axs);
        float nt = fmaf(-2.f, rcpf_(ex2(ut * (2.f * L2E)) + 1.f), 1.f);
        float zsel = g1m ? sg1 : (g2m ? ot2 : ot0);  // z_Lg at lane g
        float hn = fmaf(zsel, hp - nt, nt);
        // ---- role-gated commit (folds to one cndmask in the main loop)
        bool act = g1m ? F1 : (g2m ? F2 : (g3m ? false : F0));
        float hnw = act ? hn : hp;
        hp = hnw;
        *hw = hnw;  // 64 distinct LDS addrs: conflict-free, no predication
        // ---- read back full h vectors (broadcast b128 reads)
        float4 t;
        t = *(const float4*)&hb[wv][0][4 * g];
        hs0[0] = (v2f){t.x, t.y}; hs0[1] = (v2f){t.z, t.w};
        t = *(const float4*)&hb[wv][1][4 * g];
        hs1[0] = (v2f){t.x, t.y}; hs1[1] = (v2f){t.z, t.w};
        t = *(const float4*)&hb[wv][2][4 * g];
        hs2[0] = (v2f){t.x, t.y}; hs2[1] = (v2f){t.z, t.w};
    };

    // ---- diagonal schedule: iter k computes L0(k), L1(k-1), L2(k-2)
    step(true, false, false, 0);
    step(true, true, false, 1);
#pragma unroll 2
    for (int t0 = 2; t0 < TSTEPS; ++t0) step(true, true, true, t0);
    step(false, true, true, 0);
    step(false, false, true, 0);

    // ---- head on h2(1023) (in hb[wv][2][*])
    if (lane < 5) {
        float acc = fc_b[lane];
#pragma unroll
        for (int j = 0; j < 16; ++j)
            acc = fmaf(fc_w[lane * 16 + j], hb[wv][2][j], acc);
        out[seq * 5 + lane] = acc;
    }
}

extern "C" void kernel_launch(void* const* d_in, const int* in_sizes, int n_in,
                              void* d_out, int out_size, void* d_ws, size_t ws_size,
                              hipStream_t stream) {
    const float* x      = (const float*)d_in[0];
    const float* w_ih0  = (const float*)d_in[1];
    const float* w_ih12 = (const float*)d_in[2];
    const float* w_hh   = (const float*)d_in[3];
    const float* b_ih   = (const float*)d_in[4];
    const float* b_hh   = (const float*)d_in[5];
    const float* fc_w   = (const float*)d_in[6];
    const float* fc_b   = (const float*)d_in[7];
    float* out = (float*)d_out;

    // 4096 seqs x 64 lanes = 262144 threads = 4096 waves = 4 waves/SIMD
    gru3_quad<<<1024, 256, 0, stream>>>(
        x, w_ih0, w_ih12, w_hh, b_ih, b_hh, fc_w, fc_b, out);
}

// Round 6
// 565.495 us; speedup vs baseline: 1.5634x; 1.5634x over previous
//
#include <hip/hip_runtime.h>
#include <stdint.h>

#define TSTEPS 1024
#define L2E 1.4426950408889634f

typedef float v2f __attribute__((ext_vector_type(2)));
typedef float v4f __attribute__((ext_vector_type(4)));

__device__ __forceinline__ float rcpf_(float v) { return __builtin_amdgcn_rcpf(v); }
__device__ __forceinline__ float ex2(float v) { return __builtin_amdgcn_exp2f(v); }
#define PKFMA(a, b, c) __builtin_elementwise_fma((a), (b), (c))

// quad_perm [1,0,3,2]: exchange with lane^1 — pure VALU, fuses into v_add_dpp
__device__ __forceinline__ float dpp_x1(float v) {
    return __int_as_float(__builtin_amdgcn_update_dpp(
        0, __float_as_int(v), 0xB1, 0xF, 0xF, true));
}
// total of a v2f partial across the lane pair (16 columns)
__device__ __forceinline__ float pairsum(v2f a) {
    float s = a.x + a.y;
    return s + dpp_x1(s);
}

// Opaque loads: value is asm-produced -> cannot be rematerialized as a load.
__device__ __forceinline__ v2f ldg2(const float* p) {
    v2f r; uint64_t a = (uint64_t)p;
    asm volatile("global_load_dwordx2 %0, %1, off\n\ts_waitcnt vmcnt(0)"
                 : "=v"(r) : "v"(a));
    return r;
}
__device__ __forceinline__ float ldg1(const float* p) {
    float r; uint64_t a = (uint64_t)p;
    asm volatile("global_load_dword %0, %1, off\n\ts_waitcnt vmcnt(0)"
                 : "=v"(r) : "v"(a));
    return r;
}

__global__ __launch_bounds__(256, 2) void gru3_pair(
    const float* __restrict__ x,      // [4096,1024,1]
    const float* __restrict__ w_ih0,  // [48,1]
    const float* __restrict__ w_ih12, // [2,48,16]
    const float* __restrict__ w_hh,   // [3,48,16]
    const float* __restrict__ b_ih,   // [3,48]
    const float* __restrict__ b_hh,   // [3,48]
    const float* __restrict__ fc_w,   // [5,16]
    const float* __restrict__ fc_b,   // [5]
    float* __restrict__ out)          // [4096,5]
{
    __shared__ float xs[8][TSTEPS];  // 32 KB
    __shared__ float hb[8][4][16];   // 2 KB, [grp][layer 0..2 + pad][unit]

    const int l31 = threadIdx.x & 31;  // lane within seq group
    const int grp = threadIdx.x >> 5;  // seq slot in block (0..7)
    const int u = l31 >> 1;            // hidden unit (0..15)
    const int c = l31 & 1;             // column half; partner = lane^1
    const int c8 = c * 8;
    const int seq = blockIdx.x * 8 + grp;

    // ---- stage x (coalesced float4) + zero h buffers
    {
        const float4* xg = (const float4*)(x + (size_t)blockIdx.x * 8 * TSTEPS);
        float4* xs4 = (float4*)&xs[0][0];
#pragma unroll
        for (int j = 0; j < 8; ++j)
            xs4[threadIdx.x + 256 * j] = xg[threadIdx.x + 256 * j];
        ((float*)hb)[threadIdx.x] = 0.f;
        ((float*)hb)[256 + threadIdx.x] = 0.f;
    }

    // ---- weights (asm-pinned), pre-scaled: r/z rows by -L2E (sigmoid via
    // exp2), n rows by 2*L2E (tanh via exp2). Scale lives in the weights.
    const float qs[3] = {-L2E, -L2E, 2.f * L2E};
    v2f wh[3][3][4];  // [layer][gate r,z,n][col pair], cols c8..c8+7
    v2f wi[2][3][4];
#pragma unroll
    for (int l = 0; l < 3; ++l)
#pragma unroll
        for (int q = 0; q < 3; ++q)
#pragma unroll
            for (int m = 0; m < 4; ++m)
                wh[l][q][m] =
                    ldg2(w_hh + (l * 48 + q * 16 + u) * 16 + c8 + 2 * m) * qs[q];
#pragma unroll
    for (int l = 0; l < 2; ++l)
#pragma unroll
        for (int q = 0; q < 3; ++q)
#pragma unroll
            for (int m = 0; m < 4; ++m)
                wi[l][q][m] =
                    ldg2(w_ih12 + (l * 48 + q * 16 + u) * 16 + c8 + 2 * m) * qs[q];

    // ---- biases as accumulator seeds: contribute once after pair-reduce
    v2f bir[3], biz[3], binh[3], binx[2];
#pragma unroll
    for (int l = 0; l < 3; ++l) {
        float vr = -(ldg1(b_ih + l * 48 + u) + ldg1(b_hh + l * 48 + u)) * L2E;
        float vz = -(ldg1(b_ih + l * 48 + 16 + u) + ldg1(b_hh + l * 48 + 16 + u)) * L2E;
        float vn = ldg1(b_hh + l * 48 + 32 + u) * (2.f * L2E);
        bir[l] = (v2f){c ? 0.f : vr, 0.f};
        biz[l] = (v2f){c ? 0.f : vz, 0.f};
        binh[l] = (v2f){c ? 0.f : vn, 0.f};
    }
#pragma unroll
    for (int l = 0; l < 2; ++l) {
        float vx = ldg1(b_ih + (l + 1) * 48 + 32 + u) * (2.f * L2E);
        binx[l] = (v2f){c ? 0.f : vx, 0.f};
    }
    const float bnx0 = ldg1(b_ih + 32 + u) * (2.f * L2E);  // L0 x-side (scalar)
    const float wxr = ldg1(w_ih0 + u) * -L2E;
    const float wxz = ldg1(w_ih0 + 16 + u) * -L2E;
    const float wxn = ldg1(w_ih0 + 32 + u) * (2.f * L2E);

    __syncthreads();  // xs + hb ready

    // ---- state: per-lane col slices (8 cols = 4 v2f) + own-unit h value
    v2f h0s[4], h1s[4], h2s[4];
#pragma unroll
    for (int m = 0; m < 4; ++m) {
        h0s[m] = (v2f){0.f, 0.f};
        h1s[m] = (v2f){0.f, 0.f};
        h2s[m] = (v2f){0.f, 0.f};
    }
    float h0o = 0.f, h1o = 0.f, h2o = 0.f;

    // hoisted LDS pointers
    const float* xrow = &xs[grp][0];
    float* hw0 = &hb[grp][0][u];
    float* hw1 = &hb[grp][1][u];
    float* hw2 = &hb[grp][2][u];
    const float* hr0 = &hb[grp][0][c8];
    const float* hr1 = &hb[grp][1][c8];
    const float* hr2 = &hb[grp][2][c8];

#define RD4(dst, p)                                                       \
    do {                                                                  \
        v4f ta = *(const v4f*)(p);                                        \
        v4f tb = *(const v4f*)((p) + 4);                                  \
        dst[0] = __builtin_shufflevector(ta, ta, 0, 1);                   \
        dst[1] = __builtin_shufflevector(ta, ta, 2, 3);                   \
        dst[2] = __builtin_shufflevector(tb, tb, 0, 1);                   \
        dst[3] = __builtin_shufflevector(tb, tb, 2, 3);                   \
    } while (0)

    auto step = [&](bool F0, bool F1, bool F2, int t0) {
        v2f a;
        // ---- layer 0 (input dim 1: x-side is scalar, no reduce)
        if (F0) {
            float xt = xrow[t0];
            a = PKFMA(wh[0][0][0], h0s[0], bir[0]);
            a = PKFMA(wh[0][0][1], h0s[1], a);
            a = PKFMA(wh[0][0][2], h0s[2], a);
            a = PKFMA(wh[0][0][3], h0s[3], a);
            float sr = fmaf(wxr, xt, pairsum(a));
            a = PKFMA(wh[0][1][0], h0s[0], biz[0]);
            a = PKFMA(wh[0][1][1], h0s[1], a);
            a = PKFMA(wh[0][1][2], h0s[2], a);
            a = PKFMA(wh[0][1][3], h0s[3], a);
            float sz = fmaf(wxz, xt, pairsum(a));
            a = PKFMA(wh[0][2][0], h0s[0], binh[0]);
            a = PKFMA(wh[0][2][1], h0s[1], a);
            a = PKFMA(wh[0][2][2], h0s[2], a);
            a = PKFMA(wh[0][2][3], h0s[3], a);
            float sn = pairsum(a);
            float r = rcpf_(1.f + ex2(sr));
            float z = rcpf_(1.f + ex2(sz));
            float ut = fmaf(r, sn, fmaf(wxn, xt, bnx0));
            float n = fmaf(-2.f, rcpf_(ex2(ut) + 1.f), 1.f);
            h0o = fmaf(z, h0o - n, n);
        }
        // ---- layer 1 (consumes OLD h0s = h0(t0-1), h1s = h1(t0-2))
        if (F1) {
            a = PKFMA(wh[1][0][0], h1s[0], bir[1]);
            a = PKFMA(wh[1][0][1], h1s[1], a);
            a = PKFMA(wh[1][0][2], h1s[2], a);
            a = PKFMA(wh[1][0][3], h1s[3], a);
            a = PKFMA(wi[0][0][0], h0s[0], a);
            a = PKFMA(wi[0][0][1], h0s[1], a);
            a = PKFMA(wi[0][0][2], h0s[2], a);
            a = PKFMA(wi[0][0][3], h0s[3], a);
            float sr = pairsum(a);
            a = PKFMA(wh[1][1][0], h1s[0], biz[1]);
            a = PKFMA(wh[1][1][1], h1s[1], a);
            a = PKFMA(wh[1][1][2], h1s[2], a);
            a = PKFMA(wh[1][1][3], h1s[3], a);
            a = PKFMA(wi[0][1][0], h0s[0], a);
            a = PKFMA(wi[0][1][1], h0s[1], a);
            a = PKFMA(wi[0][1][2], h0s[2], a);
            a = PKFMA(wi[0][1][3], h0s[3], a);
            float sz = pairsum(a);
            a = PKFMA(wh[1][2][0], h1s[0], binh[1]);
            a = PKFMA(wh[1][2][1], h1s[1], a);
            a = PKFMA(wh[1][2][2], h1s[2], a);
            a = PKFMA(wh[1][2][3], h1s[3], a);
            float snh = pairsum(a);
            a = PKFMA(wi[0][2][0], h0s[0], binx[0]);
            a = PKFMA(wi[0][2][1], h0s[1], a);
            a = PKFMA(wi[0][2][2], h0s[2], a);
            a = PKFMA(wi[0][2][3], h0s[3], a);
            float snx = pairsum(a);
            float r = rcpf_(1.f + ex2(sr));
            float z = rcpf_(1.f + ex2(sz));
            float ut = fmaf(r, snh, snx);
            float n = fmaf(-2.f, rcpf_(ex2(ut) + 1.f), 1.f);
            h1o = fmaf(z, h1o - n, n);
        }
        // ---- layer 2 (consumes OLD h1s = h1(t0-2), h2s = h2(t0-3))
        if (F2) {
            a = PKFMA(wh[2][0][0], h2s[0], bir[2]);
            a = PKFMA(wh[2][0][1], h2s[1], a);
            a = PKFMA(wh[2][0][2], h2s[2], a);
            a = PKFMA(wh[2][0][3], h2s[3], a);
            a = PKFMA(wi[1][0][0], h1s[0], a);
            a = PKFMA(wi[1][0][1], h1s[1], a);
            a = PKFMA(wi[1][0][2], h1s[2], a);
            a = PKFMA(wi[1][0][3], h1s[3], a);
            float sr = pairsum(a);
            a = PKFMA(wh[2][1][0], h2s[0], biz[2]);
            a = PKFMA(wh[2][1][1], h2s[1], a);
            a = PKFMA(wh[2][1][2], h2s[2], a);
            a = PKFMA(wh[2][1][3], h2s[3], a);
            a = PKFMA(wi[1][1][0], h1s[0], a);
            a = PKFMA(wi[1][1][1], h1s[1], a);
            a = PKFMA(wi[1][1][2], h1s[2], a);
            a = PKFMA(wi[1][1][3], h1s[3], a);
            float sz = pairsum(a);
            a = PKFMA(wh[2][2][0], h2s[0], binh[2]);
            a = PKFMA(wh[2][2][1], h2s[1], a);
            a = PKFMA(wh[2][2][2], h2s[2], a);
            a = PKFMA(wh[2][2][3], h2s[3], a);
            float snh = pairsum(a);
            a = PKFMA(wi[1][2][0], h1s[0], binx[1]);
            a = PKFMA(wi[1][2][1], h1s[1], a);
            a = PKFMA(wi[1][2][2], h1s[2], a);
            a = PKFMA(wi[1][2][3], h1s[3], a);
            float snx = pairsum(a);
            float r = rcpf_(1.f + ex2(sr));
            float z = rcpf_(1.f + ex2(sz));
            float ut = fmaf(r, snh, snx);
            float n = fmaf(-2.f, rcpf_(ex2(ut) + 1.f), 1.f);
            h2o = fmaf(z, h2o - n, n);
        }
        // ---- commit (both pair lanes write same value: no conflict cost)
        if (F0) *hw0 = h0o;
        if (F1) *hw1 = h1o;
        if (F2) *hw2 = h2o;
        // ---- readback (2x ds_read_b128 per layer; wave-internal ordering)
        if (F0) RD4(h0s, hr0);
        if (F1) RD4(h1s, hr1);
        if (F2) RD4(h2s, hr2);
    };

    // ---- diagonal schedule: iter t0 computes L0(t0), L1(t0-1), L2(t0-2)
    step(true, false, false, 0);
    step(true, true, false, 1);
#pragma unroll 2
    for (int t0 = 2; t0 < TSTEPS; ++t0) step(true, true, true, t0);
    step(false, true, true, 0);
    step(false, false, true, 0);

    // ---- head on h2(1023) (in hb[grp][2][*])
    if (l31 < 5) {
        float acc = fc_b[l31];
#pragma unroll
        for (int j = 0; j < 16; ++j)
            acc = fmaf(fc_w[l31 * 16 + j], hb[grp][2][j], acc);
        out[seq * 5 + l31] = acc;
    }
#undef RD4
}

extern "C" void kernel_launch(void* const* d_in, const int* in_sizes, int n_in,
                              void* d_out, int out_size, void* d_ws, size_t ws_size,
                              hipStream_t stream) {
    const float* x      = (const float*)d_in[0];
    const float* w_ih0  = (const float*)d_in[1];
    const float* w_ih12 = (const float*)d_in[2];
    const float* w_hh   = (const float*)d_in[3];
    const float* b_ih   = (const float*)d_in[4];
    const float* b_hh   = (const float*)d_in[5];
    const float* fc_w   = (const float*)d_in[6];
    const float* fc_b   = (const float*)d_in[7];
    float* out = (float*)d_out;

    // 4096 seqs x 32 lanes = 131072 threads = 2048 waves = 2 waves/SIMD
    gru3_pair<<<512, 256, 0, stream>>>(
        x, w_ih0, w_ih12, w_hh, b_ih, b_hh, fc_w, fc_b, out);
}